// Round 8
// baseline (1469.425 us; speedup 1.0000x reference)
//
#include <hip/hip_runtime.h>
#include <hip/hip_bf16.h>

typedef unsigned int u32;
typedef unsigned long long u64;

#define H_FM 100
#define W_FM 150
#define CIN 1024
#define CMID 512
#define NPIX 15000          // H_FM * W_FM
#define NANCH 135000        // NPIX * 9
#define PRE_NMS_N 6000
#define POST_NMS_N 300
#define WPR 94              // ceil(6000/64) words per mask row

// padded A-pack geometry: rows -1..102 (104), cols -1..150 (152)
#define PW 152
#define PH 104
#define PPIX (PW * PH)          // 15808 pixels
#define CHSZ ((u64)PPIX * 64)   // bytes per (chunk) plane = 1,011,712
#define ASPLIT (32 * CHSZ)      // per split = 32,374,784
#define BSPLIT ((u64)9216 * 512 * 2)  // 9,437,184 per split

typedef __attribute__((ext_vector_type(8))) short short8;
typedef __attribute__((ext_vector_type(8))) __bf16 bf16x8;
typedef __attribute__((ext_vector_type(4))) float f32x4;

__device__ __forceinline__ u32 fkey(float f) {
  u32 u = __float_as_uint(f);
  return (u & 0x80000000u) ? ~u : (u | 0x80000000u);
}

__device__ __forceinline__ u64 shfl64(u64 v, int src) {
  u32 lo = (u32)__shfl((int)(u32)v, src, 64);
  u32 hi = (u32)__shfl((int)(u32)(v >> 32), src, 64);
  return ((u64)hi << 32) | (u64)lo;
}

// MFMA wrapper: tolerate either short8 or bf16x8 builtin operand signature.
struct FragArg {
  short8 v;
  __device__ operator short8() const { return v; }
  __device__ operator bf16x8() const { return __builtin_bit_cast(bf16x8, v); }
};
__device__ __forceinline__ f32x4 mfma16(short8 a, short8 b, f32x4 c) {
  return __builtin_amdgcn_mfma_f32_16x16x32_bf16(FragArg{a}, FragArg{b}, c, 0, 0, 0);
}

#define GLL(gp, lp) __builtin_amdgcn_global_load_lds(                        \
    (const __attribute__((address_space(1))) unsigned int*)(gp),             \
    (__attribute__((address_space(3))) unsigned int*)(lp), 16, 0, 0)

__device__ __forceinline__ void split3(float f, unsigned short& a,
                                       unsigned short& b, unsigned short& c) {
  __hip_bfloat16 h0 = __float2bfloat16(f);
  float f0 = __bfloat162float(h0);
  float r1 = f - f0;
  __hip_bfloat16 h1 = __float2bfloat16(r1);
  float r2 = r1 - __bfloat162float(h1);
  __hip_bfloat16 h2 = __float2bfloat16(r2);
  a = *(unsigned short*)&h0;
  b = *(unsigned short*)&h1;
  c = *(unsigned short*)&h2;
}

// ---------------------------------------------------------------------------
// Split fm into 3 bf16 planes packed [split][chunk32][padded pixel][64 B].
// (chunk, pixel)-major: lane reads its pixel's 32-ch slab (full lines),
// writes 64 B/split with consecutive lanes contiguous. Halo zero fused.
// ---------------------------------------------------------------------------
__global__ __launch_bounds__(256) void k_splitA(
    const float* __restrict__ src, unsigned short* __restrict__ Ap)
{
  const int id = blockIdx.x * 256 + threadIdx.x;
  // fused halo zero: 3 splits x 32 chunks x 808 halo pixels
  if (id < 3 * 32 * 808) {
    int sc = id / 808, h = id - sc * 808;
    int s = sc >> 5, c = sc & 31;
    int pp;
    if (h < 152) pp = h;                                    // row 0
    else if (h < 608) pp = 101 * 152 + (h - 152);           // rows 101..103
    else { int k = h - 608; pp = ((k >> 1) + 1) * 152 + ((k & 1) ? 151 : 0); }
    float4* dst = (float4*)((char*)Ap + (u64)s * ASPLIT + (u64)c * CHSZ + (u64)pp * 64);
    float4 zz = make_float4(0.f, 0.f, 0.f, 0.f);
    dst[0] = zz; dst[1] = zz; dst[2] = zz; dst[3] = zz;
  }
  if (id >= 32 * NPIX) return;
  const int c = id / NPIX;          // chunk 0..31
  const int p = id - c * NPIX;      // pixel
  const float* s8 = src + (size_t)p * 1024 + c * 32;
  float f[32];
  #pragma unroll
  for (int q = 0; q < 8; ++q) *(float4*)&f[q * 4] = *(const float4*)(s8 + q * 4);
  unsigned short o0[32], o1[32], o2[32];
  #pragma unroll
  for (int e = 0; e < 32; ++e) split3(f[e], o0[e], o1[e], o2[e]);
  const int yy = p / 150;
  const int pp = (yy + 1) * 152 + (p - yy * 150) + 1;
  const u64 off = (u64)c * CHSZ + (u64)pp * 64;
  #pragma unroll
  for (int q = 0; q < 4; ++q) {
    *(ushort4*)((char*)Ap + off + q * 8)                  = *(ushort4*)&o0[q * 4];
    *(ushort4*)((char*)Ap + ASPLIT + off + q * 8)         = *(ushort4*)&o1[q * 4];
    *(ushort4*)((char*)Ap + 2 * ASPLIT + off + q * 8)     = *(ushort4*)&o2[q * 4];
  }
  // note: 64 B per split = 8 ushort4? No: 32 ushorts = 64 B = 4 ushort4 of 16 B.
  #pragma unroll
  for (int q = 4; q < 8; ++q) {
    *(ushort4*)((char*)Ap + off + q * 8)                  = *(ushort4*)&o0[q * 4];
    *(ushort4*)((char*)Ap + ASPLIT + off + q * 8)         = *(ushort4*)&o1[q * 4];
    *(ushort4*)((char*)Ap + 2 * ASPLIT + off + q * 8)     = *(ushort4*)&o2[q * 4];
  }
}

// ---------------------------------------------------------------------------
// Split + transpose + pack weights: W [9216 k][512 n] fp32 ->
// 3 bf16 planes [nblk 4][seg 9][chunk 32][row 128][64 B].
// ---------------------------------------------------------------------------
__global__ __launch_bounds__(256) void k_splitB(
    const float* __restrict__ Wsrc, unsigned short* __restrict__ Bp)
{
  __shared__ float tile[64][65];
  const int k0 = blockIdx.x * 64;   // 144 blocks
  const int n0 = blockIdx.y * 64;   // 8 blocks
  const int tid = threadIdx.x;
  const int lr = tid >> 4;
  const int lc = (tid & 15) * 4;
  #pragma unroll
  for (int rr = 0; rr < 64; rr += 16) {
    float4 v = *(const float4*)&Wsrc[(size_t)(k0 + lr + rr) * CMID + n0 + lc];
    tile[lr + rr][lc + 0] = v.x; tile[lr + rr][lc + 1] = v.y;
    tile[lr + rr][lc + 2] = v.z; tile[lr + rr][lc + 3] = v.w;
  }
  __syncthreads();
  const int n = n0 + (tid >> 2);
  const int kk = k0 + (tid & 3) * 16;
  unsigned short b0[16], b1[16], b2[16];
  #pragma unroll
  for (int e = 0; e < 16; ++e)
    split3(tile[(tid & 3) * 16 + e][tid >> 2], b0[e], b1[e], b2[e]);
  const int nblk = n >> 7, row = n & 127;
  const int seg = kk >> 10, chunk = (kk >> 5) & 31, ch = kk & 31;
  u64 base = ((u64)((nblk * 9 + seg) * 32 + chunk)) * 8192 + row * 64 + ch * 2;
  #pragma unroll
  for (int q = 0; q < 4; ++q) {
    *(ushort4*)((char*)Bp + base + q * 8) = *(ushort4*)&b0[q * 4];
    *(ushort4*)((char*)Bp + BSPLIT + base + q * 8) = *(ushort4*)&b1[q * 4];
    *(ushort4*)((char*)Bp + 2 * BSPLIT + base + q * 8) = *(ushort4*)&b2[q * 4];
  }
}

// ---------------------------------------------------------------------------
// k_conv8: 128x128 tile, deterministic K-split x2 -> 944 blocks, BK=32,
// bf16x3 (6 products). XOR-swizzled LDS (conflict-free), register frag
// pre-read, single-buffer stage->compute->drain pipeline. Writes fp32
// partials (no bias/relu) to rpnP[kh].
// ---------------------------------------------------------------------------
__global__ __launch_bounds__(256, 3) void k_conv8(
    const unsigned short* __restrict__ Ap, const unsigned short* __restrict__ Bp,
    float* __restrict__ rpnP)
{
  __shared__ char lds[49152];
  const int tid = threadIdx.x;
  const int L = tid & 63;
  const int w = tid >> 6;
  const int kh = blockIdx.x / 472;          // K-half: chunks kh*16..+15
  const int bi = blockIdx.x - kh * 472;
  const int nblk = bi & 3;
  const int bn = nblk * 128;
  const int bm = (bi >> 2) * 128;
  const int wm = (w >> 1) * 64, wn = (w & 1) * 64;
  const int ch0 = kh * 16;

  const int r = L >> 2;
  const u32 dqb = (u32)(((L & 3) ^ ((r >> 1) & 3)) * 16);

  int ay[2], ax[2];
  {
    int m0 = bm + w * 16 + r;       ay[0] = m0 / 150; ax[0] = m0 - ay[0] * 150;
    int m1 = bm + (w + 4) * 16 + r; ay[1] = m1 / 150; ax[1] = m1 - ay[1] * 150;
  }
  const u32 brow0 = (u32)((w * 16 + r) * 64) + dqb;
  const u32 brow1 = (u32)(((w + 4) * 16 + r) * 64) + dqb;
  const u64 bbase = (u64)nblk * 9 * 32 * 8192;

  const int fr = L & 15, fq = L >> 4;
  const u32 fsw = (u32)((fq ^ ((fr >> 1) & 3)) * 16);
  const u32 aF = (u32)((wm >> 4) * 1024 + fr * 64) + fsw;
  const u32 bF = 24576u + (u32)((wn >> 4) * 1024 + fr * 64) + fsw;

  u32 apix[2];
  auto segSetup = [&](int seg) {
    int dy = seg / 3 - 1, dx = seg - (seg / 3) * 3 - 1;
    apix[0] = (u32)(((ay[0] + dy + 1) * 152 + ax[0] + dx + 1) * 64) + dqb;
    apix[1] = (u32)(((ay[1] + dy + 1) * 152 + ax[1] + dx + 1) * 64) + dqb;
  };

  auto stage = [&](int seg, int chunk) {
    const u64 ach = (u64)chunk * CHSZ;
    #pragma unroll
    for (int s = 0; s < 3; ++s) {
      const char* as = (const char*)Ap + (u64)s * ASPLIT + ach;
      GLL(as + apix[0], lds + s * 8192 + w * 1024);
      GLL(as + apix[1], lds + s * 8192 + (w + 4) * 1024);
    }
    const u64 bch = bbase + (u64)(seg * 32 + chunk) * 8192;
    #pragma unroll
    for (int s = 0; s < 3; ++s) {
      const char* bs = (const char*)Bp + (u64)s * BSPLIT + bch;
      GLL(bs + brow0, lds + 24576 + s * 8192 + w * 1024);
      GLL(bs + brow1, lds + 24576 + s * 8192 + (w + 4) * 1024);
    }
  };

  short8 Af[3][4], Bf[3][4];
  auto readFrags = [&]() {
    #pragma unroll
    for (int s = 0; s < 3; ++s)
      #pragma unroll
      for (int i = 0; i < 4; ++i) {
        Af[s][i] = *(const short8*)(lds + aF + s * 8192 + i * 1024);
        Bf[s][i] = *(const short8*)(lds + bF + s * 8192 + i * 1024);
      }
  };

  f32x4 acc[4][4];
  #pragma unroll
  for (int i = 0; i < 4; ++i)
    #pragma unroll
    for (int j = 0; j < 4; ++j) acc[i][j] = (f32x4){0.f, 0.f, 0.f, 0.f};

  segSetup(0);
  stage(0, ch0);
  __syncthreads();
  readFrags();

  for (int it = 0; it < 144; ++it) {          // it = seg*16 + (chunk - ch0)
    const int nit = it + 1;
    const bool more = nit < 144;
    if (more && (nit & 15) == 0) segSetup(nit >> 4);
    __syncthreads();                          // all waves hold frags in regs
    if (more) stage(nit >> 4, ch0 + (nit & 15));
    #pragma unroll
    for (int i = 0; i < 4; ++i)
      #pragma unroll
      for (int j = 0; j < 4; ++j) {
        f32x4 c = acc[i][j];
        c = mfma16(Af[0][i], Bf[0][j], c);
        c = mfma16(Af[0][i], Bf[1][j], c);
        c = mfma16(Af[1][i], Bf[0][j], c);
        c = mfma16(Af[1][i], Bf[1][j], c);
        c = mfma16(Af[0][i], Bf[2][j], c);
        c = mfma16(Af[2][i], Bf[0][j], c);
        acc[i][j] = c;
      }
    __syncthreads();                          // staged chunk landed
    if (more) readFrags();
  }

  // epilogue: raw partial store (C/D: row=(lane>>4)*4+reg, col=lane&15)
  float* outP = rpnP + (size_t)kh * NPIX * CMID;
  #pragma unroll
  for (int i = 0; i < 4; ++i) {
    const int mb = bm + wm + i * 16 + ((L >> 4) << 2);
    #pragma unroll
    for (int ri = 0; ri < 4; ++ri) {
      const int m = mb + ri;
      if (m < NPIX) {
        float* op = outP + (size_t)m * CMID;
        #pragma unroll
        for (int j = 0; j < 4; ++j) {
          const int n = bn + wn + j * 16 + (L & 15);
          op[n] = acc[i][j][ri];
        }
      }
    }
  }
}

// ---------------------------------------------------------------------------
// Pack head weights Wp[512][64] + bp[64]; fused: zero hist + ctl.
// ---------------------------------------------------------------------------
__global__ __launch_bounds__(256) void k_packW(
    const float* __restrict__ Ws, const float* __restrict__ bs,
    const float* __restrict__ Wb, const float* __restrict__ bb,
    float* __restrict__ Wp, float* __restrict__ bp,
    u32* __restrict__ hist, u32* __restrict__ ctl)
{
  int tt = blockIdx.x * 256 + threadIdx.x;
  int k = tt >> 6, o = tt & 63;
  float v = (o < 18) ? Ws[k * 18 + o] : ((o < 54) ? Wb[k * 36 + (o - 18)] : 0.f);
  Wp[tt] = v;
  if (tt < 64) bp[tt] = (tt < 18) ? bs[tt] : ((tt < 54) ? bb[tt - 18] : 0.f);
  if (tt < 256) hist[tt] = 0;
  if (tt < 16) ctl[tt] = 0;
  if (tt == 1) ctl[1] = PRE_NMS_N;   // kneed
}

// ---------------------------------------------------------------------------
// Head GEMM + fused conv-reduce (p0+p1+bias, relu) + fused decode.
// 472 blocks x 32 rows.
// ---------------------------------------------------------------------------
__global__ __launch_bounds__(256) void k_headdec(
    const float* __restrict__ rpnP, const float* __restrict__ br,
    const float* __restrict__ Wp, const float* __restrict__ bp,
    const int* __restrict__ img,
    float* __restrict__ fg, float4* __restrict__ boxes)
{
  __shared__ float As[32][33];
  __shared__ float Bs[32][64];
  __shared__ float vs[32 * 64];
  const int tid = threadIdx.x;
  const int bm = blockIdx.x * 32;
  const int r  = tid >> 3;          // row 0..31 (load & compute)
  const int kg = tid & 7;           // A-load k-group
  const int c8 = (tid & 7) * 8;     // compute col base
  const int n4 = (tid & 15) * 4;    // B-load
  const int kr = tid >> 4;          // B-load row 0..15
  const float4 z4 = make_float4(0.f, 0.f, 0.f, 0.f);
  const float* p0 = rpnP;
  const float* p1 = rpnP + (size_t)NPIX * CMID;

  float acc[8];
  #pragma unroll
  for (int j = 0; j < 8; ++j) acc[j] = 0.f;

  for (int kc = 0; kc < 512; kc += 32) {
    __syncthreads();
    {
      int m = bm + r;
      float4 v0 = z4, v1 = z4;
      if (m < NPIX) {
        size_t o = (size_t)m * CMID + kc + kg * 4;
        v0 = *(const float4*)&p0[o];
        v1 = *(const float4*)&p1[o];
      }
      float4 bb = *(const float4*)&br[kc + kg * 4];
      As[kg * 4 + 0][r] = fmaxf(v0.x + v1.x + bb.x, 0.f);
      As[kg * 4 + 1][r] = fmaxf(v0.y + v1.y + bb.y, 0.f);
      As[kg * 4 + 2][r] = fmaxf(v0.z + v1.z + bb.z, 0.f);
      As[kg * 4 + 3][r] = fmaxf(v0.w + v1.w + bb.w, 0.f);
    }
    *(float4*)&Bs[kr][n4]      = *(const float4*)&Wp[(kc + kr) * 64 + n4];
    *(float4*)&Bs[kr + 16][n4] = *(const float4*)&Wp[(kc + kr + 16) * 64 + n4];
    __syncthreads();
    #pragma unroll
    for (int kk = 0; kk < 32; ++kk) {
      float a = As[kk][r];
      float4 b0 = *(const float4*)&Bs[kk][c8];
      float4 b1 = *(const float4*)&Bs[kk][c8 + 4];
      acc[0] = fmaf(a, b0.x, acc[0]); acc[1] = fmaf(a, b0.y, acc[1]);
      acc[2] = fmaf(a, b0.z, acc[2]); acc[3] = fmaf(a, b0.w, acc[3]);
      acc[4] = fmaf(a, b1.x, acc[4]); acc[5] = fmaf(a, b1.y, acc[5]);
      acc[6] = fmaf(a, b1.z, acc[6]); acc[7] = fmaf(a, b1.w, acc[7]);
    }
  }
  __syncthreads();
  #pragma unroll
  for (int j = 0; j < 8; ++j) vs[r * 64 + c8 + j] = acc[j] + bp[c8 + j];
  __syncthreads();

  const float AW[9] = {184.f, 368.f, 736.f, 128.f, 256.f, 512.f,  88.f, 176.f, 352.f};
  const float AH[9] = { 96.f, 192.f, 384.f, 128.f, 256.f, 512.f, 176.f, 352.f, 704.f};
  const float imh1 = (float)img[0] - 1.f;
  const float imw1 = (float)img[1] - 1.f;
  for (int id = tid; id < 32 * 9; id += 256) {
    int pl = id / 9, a = id - pl * 9;
    int p = bm + pl;
    if (p >= NPIX) break;
    const float* row = vs + pl * 64;
    const int y = p / W_FM, x = p - y * W_FM;

    float c0 = row[2 * a], c1 = row[2 * a + 1];
    float score = 1.f / (1.f + expf(c0 - c1));

    float dxv = row[18 + 4 * a + 0];
    float dyv = row[18 + 4 * a + 1];
    float dwv = row[18 + 4 * a + 2];
    float dhv = row[18 + 4 * a + 3];

    float aw = AW[a], ah = AH[a];
    float acx = (float)(x * 16 + 8);
    float acy = (float)(y * 16 + 8);
    float pcx = dxv * aw + acx;
    float pcy = dyv * ah + acy;
    float pw = expf(dwv) * aw;
    float ph = expf(dhv) * ah;

    float b0 = fminf(fmaxf(pcx - 0.5f * pw, 0.f), imw1);
    float b1 = fminf(fmaxf(pcy - 0.5f * ph, 0.f), imh1);
    float b2 = fminf(fmaxf(pcx + 0.5f * pw, 0.f), imw1);
    float b3 = fminf(fmaxf(pcy + 0.5f * ph, 0.f), imh1);

    float bw = b2 - b0 + 1.f, bh = b3 - b1 + 1.f;
    if (!(bw >= 16.f && bh >= 16.f)) score = -1e9f;

    int gi = p * 9 + a;
    fg[gi] = score;
    boxes[gi] = make_float4(b0, b1, b2, b3);
  }
}

// ---------------------------------------------------------------------------
// Radix-select (exact top-6000 threshold).
// ctl[0]=prefix/threshold, ctl[1]=kneed, ctl[2]=cntA, ctl[3]=cntB, ctl[8]=nvalid
// ---------------------------------------------------------------------------
__global__ __launch_bounds__(256) void k_hist(
    const float* __restrict__ fg, u32* __restrict__ hist,
    const u32* __restrict__ ctl, int pass)
{
  __shared__ u32 h[256];
  h[threadIdx.x] = 0;
  __syncthreads();
  const int shift = 24 - 8 * pass;
  const u32 prefix = ctl[0];
  for (int i = blockIdx.x * 256 + threadIdx.x; i < NANCH; i += 128 * 256) {
    u32 key = fkey(fg[i]);
    bool match = (pass == 0) || ((key >> (shift + 8)) == prefix);
    if (match) atomicAdd(&h[(key >> shift) & 255], 1u);
  }
  __syncthreads();
  u32 c = h[threadIdx.x];
  if (c) atomicAdd(&hist[threadIdx.x], c);
}

__global__ void k_scan(u32* __restrict__ hist, u32* __restrict__ ctl) {
  if (threadIdx.x == 0) {
    u32 kneed = ctl[1];
    u32 cum = 0;
    int d = 0;
    for (int dd = 255; dd >= 0; --dd) {
      u32 c = hist[dd];
      if (cum + c >= kneed) { d = dd; break; }
      cum += c;
    }
    ctl[0] = (ctl[0] << 8) | (u32)d;
    ctl[1] = kneed - cum;
  }
  __syncthreads();
  hist[threadIdx.x] = 0;
}

__global__ __launch_bounds__(256) void k_compact(
    const float* __restrict__ fg, u32* __restrict__ ctl,
    u64* __restrict__ listA, u32* __restrict__ listB)
{
  int i = blockIdx.x * 256 + threadIdx.x;
  if (i >= NANCH) return;
  u32 T = ctl[0];
  u32 key = fkey(fg[i]);
  if (key > T) {
    u32 slot = atomicAdd(&ctl[2], 1u);
    listA[slot] = ((u64)key << 32) | (u64)(0xFFFFFFFFu - (u32)i);
  } else if (key == T) {
    u32 slot = atomicAdd(&ctl[3], 1u);
    if (slot < 8192) listB[slot] = (u32)i;
  }
}

__global__ __launch_bounds__(256) void k_tiefix(
    u32* __restrict__ ctl, const u32* __restrict__ listB, u64* __restrict__ listA)
{
  __shared__ u32 s[8192];
  const int tid = threadIdx.x;
  const u32 kneed = ctl[1];
  const u32 base = ctl[2];
  const u32 cntB = min(ctl[3], 8192u);
  const u32 T = ctl[0];
  if (kneed == 0) return;
  if (cntB == kneed) {
    for (u32 t = tid; t < kneed; t += 256)
      listA[base + t] = ((u64)T << 32) | (u64)(0xFFFFFFFFu - listB[t]);
    return;
  }
  u32 n2 = 1;
  while (n2 < cntB) n2 <<= 1;
  for (u32 i = tid; i < n2; i += 256) s[i] = (i < cntB) ? listB[i] : 0xFFFFFFFFu;
  __syncthreads();
  for (u32 k = 2; k <= n2; k <<= 1) {
    for (u32 j = k >> 1; j > 0; j >>= 1) {
      for (u32 i = tid; i < n2; i += 256) {
        u32 ixj = i ^ j;
        if (ixj > i) {
          u32 a = s[i], b = s[ixj];
          bool up = ((i & k) == 0);
          if ((a > b) == up) { s[i] = b; s[ixj] = a; }
        }
      }
      __syncthreads();
    }
  }
  for (u32 t = tid; t < kneed; t += 256)
    listA[base + t] = ((u64)T << 32) | (u64)(0xFFFFFFFFu - s[t]);
}

__global__ __launch_bounds__(1024) void k_sort(
    const u64* __restrict__ listA, u64* __restrict__ sorted)
{
  __shared__ u64 s[8192];
  const int tid = threadIdx.x;
  for (int i = tid; i < 8192; i += 1024) s[i] = (i < PRE_NMS_N) ? listA[i] : 0ull;
  __syncthreads();
  for (int k = 2; k <= 8192; k <<= 1) {
    for (int j = k >> 1; j > 0; j >>= 1) {
      for (int i = tid; i < 8192; i += 1024) {
        int ixj = i ^ j;
        if (ixj > i) {
          u64 a = s[i], b = s[ixj];
          bool up = ((i & k) == 0);
          if ((a < b) == up) { s[i] = b; s[ixj] = a; }
        }
      }
      __syncthreads();
    }
  }
  for (int i = tid; i < 8192; i += 1024) sorted[i] = s[i];
}

// gather top boxes; fused: count valid (score > -1e8) into ctl[8]
__global__ __launch_bounds__(256) void k_gather(
    const u64* __restrict__ sorted, const float4* __restrict__ boxes,
    float4* __restrict__ tb, u32* __restrict__ ctl)
{
  int t = blockIdx.x * 256 + threadIdx.x;
  const u32 kcut = fkey(-1e8f);
  bool inb = t < PRE_NMS_N;
  u64 p = inb ? sorted[t] : 0ull;
  bool valid = inb && ((u32)(p >> 32) > kcut);
  u64 ball = __ballot(valid);
  if ((threadIdx.x & 63) == 0 && ball) atomicAdd(&ctl[8], (u32)__popcll(ball));
  if (!inb) return;
  u32 idx = 0xFFFFFFFFu - (u32)(p & 0xFFFFFFFFull);
  tb[t] = boxes[idx];
}

// ---------------------------------------------------------------------------
// Suppression bitmask: mask[i][w] bit b == (IoU(i, w*64+b) > 0.7 && j > i)
// ---------------------------------------------------------------------------
__global__ __launch_bounds__(64) void k_mask(
    const float4* __restrict__ tb, u64* __restrict__ mask)
{
  __shared__ float4 cb[64];
  const int bj = blockIdx.x, bi = blockIdx.y, t = threadIdx.x;
  const int j0 = bj * 64;
  const int jn = min(64, PRE_NMS_N - j0);
  if (t < jn) cb[t] = tb[j0 + t];
  __syncthreads();
  const int i = bi * 64 + t;
  if (i >= PRE_NMS_N) return;
  const float4 b = tb[i];
  const float ai = (b.z - b.x + 1.f) * (b.w - b.y + 1.f);
  u64 bits = 0;
  for (int tt = 0; tt < jn; ++tt) {
    int j = j0 + tt;
    if (j <= i) continue;
    float4 c = cb[tt];
    float iw = fminf(b.z, c.z) - fmaxf(b.x, c.x) + 1.f;
    float ih = fminf(b.w, c.w) - fmaxf(b.y, c.y) + 1.f;
    float inter = fmaxf(iw, 0.f) * fmaxf(ih, 0.f);
    float aj = (c.z - c.x + 1.f) * (c.w - c.y + 1.f);
    float iou = inter / (ai + aj - inter);
    if (iou > 0.7f) bits |= (1ull << tt);
  }
  mask[(size_t)i * WPR + bj] = bits;
}

// ---------------------------------------------------------------------------
// Single-wave greedy NMS walk, word-level ffs scanning over live bits.
// removed-bitmask in registers (lane -> words lane, lane+64). Early exit @300.
// ---------------------------------------------------------------------------
__global__ __launch_bounds__(64) void k_nms(
    const u64* __restrict__ mask, const float* __restrict__ tb,
    const u32* __restrict__ ctl, float* __restrict__ out)
{
  const int lane = threadIdx.x;
  const int nvalid = min((int)ctl[8], PRE_NMS_N);
  u64 r0 = 0, r1 = 0;
  int kept = 0;
  for (int w = 0; w < WPR && kept < POST_NMS_N; ++w) {
    const int base = w << 6;
    if (base >= nvalid) break;
    u64 rw = (w < 64) ? shfl64(r0, w) : shfl64(r1, w - 64);
    u64 live = ~rw;
    if (base + 64 > nvalid) live &= ((1ull << (nvalid - base)) - 1ull);
    while (live) {
      int b = (int)(__ffsll((long long)live) - 1);
      int i = base + b;
      if (lane < 4) out[kept * 4 + lane] = tb[i * 4 + lane];
      ++kept;
      if (kept >= POST_NMS_N) break;
      const u64* row = mask + (size_t)i * WPR;
      u64 m0 = row[lane];
      u64 m1 = (lane < WPR - 64) ? row[64 + lane] : 0ull;
      r0 |= m0; r1 |= m1;
      u64 rwi = (w < 64) ? shfl64(m0, w) : shfl64(m1, w - 64);
      live &= ~rwi;
      live = (b == 63) ? 0ull : (live & (~0ull << (b + 1)));
    }
  }
  for (int j = kept * 4 + lane; j < POST_NMS_N * 4; j += 64) out[j] = 0.f;
}

// ---------------------------------------------------------------------------
extern "C" void kernel_launch(void* const* d_in, const int* in_sizes, int n_in,
                              void* d_out, int out_size, void* d_ws, size_t ws_size,
                              hipStream_t stream) {
  const float* fm  = (const float*)d_in[0];
  const float* Wr  = (const float*)d_in[1];
  const float* br  = (const float*)d_in[2];
  const float* Wsc = (const float*)d_in[3];
  const float* bsc = (const float*)d_in[4];
  const float* Wbb = (const float*)d_in[5];
  const float* bbb = (const float*)d_in[6];
  const int*   img = (const int*)d_in[7];
  float* out = (float*)d_out;

  char* w = (char*)d_ws;
  size_t off = 0;
  auto alloc = [&](size_t bytes) {
    size_t p = off;
    off = (off + bytes + 255) & ~(size_t)255;
    return p;
  };
  float* rpnP   = (float*)(w + alloc((size_t)2 * NPIX * CMID * 4));   // 61.44 MB
  u32* hist     = (u32*)(w + alloc(1024));
  u32* ctl      = (u32*)(w + alloc(64));
  u64* listA    = (u64*)(w + alloc((size_t)PRE_NMS_N * 8));
  u32* listB    = (u32*)(w + alloc(8192 * 4));
  u64* sorted   = (u64*)(w + alloc(8192 * 8));
  float* Wp     = (float*)(w + alloc(512 * 64 * 4));
  float* bp     = (float*)(w + alloc(64 * 4));
  unsigned short* Ap = (unsigned short*)(w + alloc((size_t)(3 * ASPLIT))); // 97.1 MB
  unsigned short* Bp = (unsigned short*)(w + alloc((size_t)(3 * BSPLIT))); // 28.3 MB
  // post-conv overlays inside the (then-dead) Ap region:
  char* ov = (char*)Ap;
  float* fg     = (float*)ov;                               ov += ((size_t)NANCH * 4 + 255) & ~(size_t)255;
  float4* boxes = (float4*)ov;                              ov += ((size_t)NANCH * 16 + 255) & ~(size_t)255;
  float4* topbox= (float4*)ov;                              ov += ((size_t)PRE_NMS_N * 16 + 255) & ~(size_t)255;
  u64* mask     = (u64*)ov;                                 // 4.5 MB, still < ASPLIT

  // 1. precision-split + pack (halo-zero fused in splitA; hist/ctl init in packW)
  k_splitA<<<dim3((32 * NPIX + 255) / 256), dim3(256), 0, stream>>>(fm, Ap);
  k_splitB<<<dim3(144, 8), dim3(256), 0, stream>>>(Wr, Bp);
  k_packW<<<dim3(128), dim3(256), 0, stream>>>(Wsc, bsc, Wbb, bbb, Wp, bp, hist, ctl);
  // 2. conv (3x3), K-split x2, pipelined swizzled MFMA -> fp32 partials
  k_conv8<<<dim3(118 * 4 * 2), dim3(256), 0, stream>>>(Ap, Bp, rpnP);
  // 3. heads (+ fused conv-reduce/bias/relu) + fused decode
  k_headdec<<<dim3(472), dim3(256), 0, stream>>>(rpnP, br, Wp, bp, img, fg, boxes);
  // 4. exact top-6000 radix select
  for (int pass = 0; pass < 4; ++pass) {
    k_hist<<<128, 256, 0, stream>>>(fg, hist, ctl, pass);
    k_scan<<<1, 256, 0, stream>>>(hist, ctl);
  }
  k_compact<<<(NANCH + 255) / 256, 256, 0, stream>>>(fg, ctl, listA, listB);
  k_tiefix<<<1, 256, 0, stream>>>(ctl, listB, listA);
  // 5. sort (desc score, asc index) + gather (+ valid count)
  k_sort<<<1, 1024, 0, stream>>>(listA, sorted);
  k_gather<<<(PRE_NMS_N + 255) / 256, 256, 0, stream>>>(sorted, boxes, topbox, ctl);
  // 6. NMS mask + single-wave ffs walk + emit 300
  k_mask<<<dim3(WPR, WPR), 64, 0, stream>>>(topbox, mask);
  k_nms<<<1, 64, 0, stream>>>(mask, (const float*)topbox, ctl, out);
}

// Round 9
// 1137.929 us; speedup vs baseline: 1.2913x; 1.2913x over previous
//
#include <hip/hip_runtime.h>
#include <hip/hip_bf16.h>

typedef unsigned int u32;
typedef unsigned long long u64;

#define H_FM 100
#define W_FM 150
#define CIN 1024
#define CMID 512
#define NPIX 15000          // H_FM * W_FM
#define NANCH 135000        // NPIX * 9
#define PRE_NMS_N 6000
#define POST_NMS_N 300
#define WPR 94              // ceil(6000/64) words per mask row

// padded A-pack geometry: rows -1..102 (104), cols -1..150 (152)
#define PW 152
#define PH 104
#define PPIX (PW * PH)          // 15808 pixels
#define CHSZ ((u64)PPIX * 64)   // bytes per (chunk) plane = 1,011,712
#define ASPLIT (32 * CHSZ)      // per split = 32,374,784
#define BSPLIT ((u64)9216 * 512 * 2)  // 9,437,184 per split

typedef __attribute__((ext_vector_type(8))) short short8;
typedef __attribute__((ext_vector_type(8))) __bf16 bf16x8;
typedef __attribute__((ext_vector_type(4))) float f32x4;

__device__ __forceinline__ u32 fkey(float f) {
  u32 u = __float_as_uint(f);
  return (u & 0x80000000u) ? ~u : (u | 0x80000000u);
}

__device__ __forceinline__ u64 shfl64(u64 v, int src) {
  u32 lo = (u32)__shfl((int)(u32)v, src, 64);
  u32 hi = (u32)__shfl((int)(u32)(v >> 32), src, 64);
  return ((u64)hi << 32) | (u64)lo;
}

// MFMA wrapper: tolerate either short8 or bf16x8 builtin operand signature.
struct FragArg {
  short8 v;
  __device__ operator short8() const { return v; }
  __device__ operator bf16x8() const { return __builtin_bit_cast(bf16x8, v); }
};
__device__ __forceinline__ f32x4 mfma16(short8 a, short8 b, f32x4 c) {
  return __builtin_amdgcn_mfma_f32_16x16x32_bf16(FragArg{a}, FragArg{b}, c, 0, 0, 0);
}

#define GLL(gp, lp) __builtin_amdgcn_global_load_lds(                        \
    (const __attribute__((address_space(1))) unsigned int*)(gp),             \
    (__attribute__((address_space(3))) unsigned int*)(lp), 16, 0, 0)

__device__ __forceinline__ void split3(float f, unsigned short& a,
                                       unsigned short& b, unsigned short& c) {
  __hip_bfloat16 h0 = __float2bfloat16(f);
  float f0 = __bfloat162float(h0);
  float r1 = f - f0;
  __hip_bfloat16 h1 = __float2bfloat16(r1);
  float r2 = r1 - __bfloat162float(h1);
  __hip_bfloat16 h2 = __float2bfloat16(r2);
  a = *(unsigned short*)&h0;
  b = *(unsigned short*)&h1;
  c = *(unsigned short*)&h2;
}

// ---------------------------------------------------------------------------
// Split fm into 3 bf16 planes packed [split][chunk32][padded pixel][64 B].
// (chunk, pixel)-major: lane reads its pixel's 32-ch slab (full lines),
// writes 64 B/split with consecutive lanes contiguous. Halo zero fused.
// ---------------------------------------------------------------------------
__global__ __launch_bounds__(256) void k_splitA(
    const float* __restrict__ src, unsigned short* __restrict__ Ap)
{
  const int id = blockIdx.x * 256 + threadIdx.x;
  // fused halo zero: 3 splits x 32 chunks x 808 halo pixels
  if (id < 3 * 32 * 808) {
    int sc = id / 808, h = id - sc * 808;
    int s = sc >> 5, c = sc & 31;
    int pp;
    if (h < 152) pp = h;                                    // row 0
    else if (h < 608) pp = 101 * 152 + (h - 152);           // rows 101..103
    else { int k = h - 608; pp = ((k >> 1) + 1) * 152 + ((k & 1) ? 151 : 0); }
    float4* dst = (float4*)((char*)Ap + (u64)s * ASPLIT + (u64)c * CHSZ + (u64)pp * 64);
    float4 zz = make_float4(0.f, 0.f, 0.f, 0.f);
    dst[0] = zz; dst[1] = zz; dst[2] = zz; dst[3] = zz;
  }
  if (id >= 32 * NPIX) return;
  const int c = id / NPIX;          // chunk 0..31
  const int p = id - c * NPIX;      // pixel
  const float* s8 = src + (size_t)p * 1024 + c * 32;
  float f[32];
  #pragma unroll
  for (int q = 0; q < 8; ++q) *(float4*)&f[q * 4] = *(const float4*)(s8 + q * 4);
  unsigned short o0[32], o1[32], o2[32];
  #pragma unroll
  for (int e = 0; e < 32; ++e) split3(f[e], o0[e], o1[e], o2[e]);
  const int yy = p / 150;
  const int pp = (yy + 1) * 152 + (p - yy * 150) + 1;
  const u64 off = (u64)c * CHSZ + (u64)pp * 64;
  #pragma unroll
  for (int q = 0; q < 8; ++q) {
    *(ushort4*)((char*)Ap + off + q * 8)              = *(ushort4*)&o0[q * 4];
    *(ushort4*)((char*)Ap + ASPLIT + off + q * 8)     = *(ushort4*)&o1[q * 4];
    *(ushort4*)((char*)Ap + 2 * ASPLIT + off + q * 8) = *(ushort4*)&o2[q * 4];
  }
}

// ---------------------------------------------------------------------------
// Split + transpose + pack weights: W [9216 k][512 n] fp32 ->
// 3 bf16 planes [nblk 4][seg 9][chunk 32][row 128][64 B].
// ---------------------------------------------------------------------------
__global__ __launch_bounds__(256) void k_splitB(
    const float* __restrict__ Wsrc, unsigned short* __restrict__ Bp)
{
  __shared__ float tile[64][65];
  const int k0 = blockIdx.x * 64;   // 144 blocks
  const int n0 = blockIdx.y * 64;   // 8 blocks
  const int tid = threadIdx.x;
  const int lr = tid >> 4;
  const int lc = (tid & 15) * 4;
  #pragma unroll
  for (int rr = 0; rr < 64; rr += 16) {
    float4 v = *(const float4*)&Wsrc[(size_t)(k0 + lr + rr) * CMID + n0 + lc];
    tile[lr + rr][lc + 0] = v.x; tile[lr + rr][lc + 1] = v.y;
    tile[lr + rr][lc + 2] = v.z; tile[lr + rr][lc + 3] = v.w;
  }
  __syncthreads();
  const int n = n0 + (tid >> 2);
  const int kk = k0 + (tid & 3) * 16;
  unsigned short b0[16], b1[16], b2[16];
  #pragma unroll
  for (int e = 0; e < 16; ++e)
    split3(tile[(tid & 3) * 16 + e][tid >> 2], b0[e], b1[e], b2[e]);
  const int nblk = n >> 7, row = n & 127;
  const int seg = kk >> 10, chunk = (kk >> 5) & 31, ch = kk & 31;
  u64 base = ((u64)((nblk * 9 + seg) * 32 + chunk)) * 8192 + row * 64 + ch * 2;
  #pragma unroll
  for (int q = 0; q < 4; ++q) {
    *(ushort4*)((char*)Bp + base + q * 8) = *(ushort4*)&b0[q * 4];
    *(ushort4*)((char*)Bp + BSPLIT + base + q * 8) = *(ushort4*)&b1[q * 4];
    *(ushort4*)((char*)Bp + 2 * BSPLIT + base + q * 8) = *(ushort4*)&b2[q * 4];
  }
}

// ---------------------------------------------------------------------------
// k_conv8: 128x128 tile, BK=32, bf16x3 (6 products), XOR-swizzled LDS,
// register frag pre-read, single-buffer stage->compute->drain pipeline.
// XCD-aware block mapping: XCD x (= blockIdx%8) hosts m-tiles {8q+x} x all
// 4 n-tiles, so co-resident same-XCD blocks share A slabs (4 readers) and
// B slabs (15 readers) in its L2. Grid 480 (8 idle blocks exit).
// ---------------------------------------------------------------------------
__global__ __launch_bounds__(256, 2) void k_conv8(
    const unsigned short* __restrict__ Ap, const unsigned short* __restrict__ Bp,
    const float* __restrict__ br, float* __restrict__ rpn)
{
  __shared__ char lds[49152];
  const int gb = blockIdx.x;
  const int xcd = gb & 7;
  const int nblk = (gb >> 3) & 3;
  const int bmi = (gb >> 5) * 8 + xcd;
  if (bmi >= 118) return;
  const int bn = nblk * 128;
  const int bm = bmi * 128;
  const int tid = threadIdx.x;
  const int L = tid & 63;
  const int w = tid >> 6;
  const int wm = (w >> 1) * 64, wn = (w & 1) * 64;

  const int r = L >> 2;
  const u32 dqb = (u32)(((L & 3) ^ ((r >> 1) & 3)) * 16);

  int ay[2], ax[2];
  {
    int m0 = bm + w * 16 + r;       ay[0] = m0 / 150; ax[0] = m0 - ay[0] * 150;
    int m1 = bm + (w + 4) * 16 + r; ay[1] = m1 / 150; ax[1] = m1 - ay[1] * 150;
  }
  const u32 brow0 = (u32)((w * 16 + r) * 64) + dqb;
  const u32 brow1 = (u32)(((w + 4) * 16 + r) * 64) + dqb;
  const u64 bbase = (u64)nblk * 9 * 32 * 8192;

  const int fr = L & 15, fq = L >> 4;
  const u32 fsw = (u32)((fq ^ ((fr >> 1) & 3)) * 16);
  const u32 aF = (u32)((wm >> 4) * 1024 + fr * 64) + fsw;
  const u32 bF = 24576u + (u32)((wn >> 4) * 1024 + fr * 64) + fsw;

  u32 apix[2];
  auto segSetup = [&](int seg) {
    int dy = seg / 3 - 1, dx = seg - (seg / 3) * 3 - 1;
    apix[0] = (u32)(((ay[0] + dy + 1) * 152 + ax[0] + dx + 1) * 64) + dqb;
    apix[1] = (u32)(((ay[1] + dy + 1) * 152 + ax[1] + dx + 1) * 64) + dqb;
  };

  auto stage = [&](int seg, int chunk) {
    const u64 ach = (u64)chunk * CHSZ;
    #pragma unroll
    for (int s = 0; s < 3; ++s) {
      const char* as = (const char*)Ap + (u64)s * ASPLIT + ach;
      GLL(as + apix[0], lds + s * 8192 + w * 1024);
      GLL(as + apix[1], lds + s * 8192 + (w + 4) * 1024);
    }
    const u64 bch = bbase + (u64)(seg * 32 + chunk) * 8192;
    #pragma unroll
    for (int s = 0; s < 3; ++s) {
      const char* bs = (const char*)Bp + (u64)s * BSPLIT + bch;
      GLL(bs + brow0, lds + 24576 + s * 8192 + w * 1024);
      GLL(bs + brow1, lds + 24576 + s * 8192 + (w + 4) * 1024);
    }
  };

  short8 Af[3][4], Bf[3][4];
  auto readFrags = [&]() {
    #pragma unroll
    for (int s = 0; s < 3; ++s)
      #pragma unroll
      for (int i = 0; i < 4; ++i) {
        Af[s][i] = *(const short8*)(lds + aF + s * 8192 + i * 1024);
        Bf[s][i] = *(const short8*)(lds + bF + s * 8192 + i * 1024);
      }
  };

  f32x4 acc[4][4];
  #pragma unroll
  for (int i = 0; i < 4; ++i)
    #pragma unroll
    for (int j = 0; j < 4; ++j) acc[i][j] = (f32x4){0.f, 0.f, 0.f, 0.f};

  segSetup(0);
  stage(0, 0);
  __syncthreads();
  readFrags();

  for (int it = 0; it < 288; ++it) {          // it = seg*32 + chunk
    const int nit = it + 1;
    const bool more = nit < 288;
    if (more && (nit & 31) == 0) segSetup(nit >> 5);
    __syncthreads();                          // all waves hold frags in regs
    if (more) stage(nit >> 5, nit & 31);      // overwrite LDS; drain overlapped
    #pragma unroll
    for (int i = 0; i < 4; ++i)
      #pragma unroll
      for (int j = 0; j < 4; ++j) {
        f32x4 c = acc[i][j];
        c = mfma16(Af[0][i], Bf[0][j], c);
        c = mfma16(Af[0][i], Bf[1][j], c);
        c = mfma16(Af[1][i], Bf[0][j], c);
        c = mfma16(Af[1][i], Bf[1][j], c);
        c = mfma16(Af[0][i], Bf[2][j], c);
        c = mfma16(Af[2][i], Bf[0][j], c);
        acc[i][j] = c;
      }
    __syncthreads();                          // staged chunk landed
    if (more) readFrags();
  }

  // epilogue: bias + relu + store (C/D: row=(lane>>4)*4+reg, col=lane&15)
  #pragma unroll
  for (int i = 0; i < 4; ++i) {
    const int mb = bm + wm + i * 16 + ((L >> 4) << 2);
    #pragma unroll
    for (int ri = 0; ri < 4; ++ri) {
      const int m = mb + ri;
      if (m < NPIX) {
        float* op = rpn + (size_t)m * CMID;
        #pragma unroll
        for (int j = 0; j < 4; ++j) {
          const int n = bn + wn + j * 16 + (L & 15);
          op[n] = fmaxf(acc[i][j][ri] + br[n], 0.f);
        }
      }
    }
  }
}

// ---------------------------------------------------------------------------
// Pack head weights Wp[512][64] + bp[64]; fused: zero hist + ctl.
// ---------------------------------------------------------------------------
__global__ __launch_bounds__(256) void k_packW(
    const float* __restrict__ Ws, const float* __restrict__ bs,
    const float* __restrict__ Wb, const float* __restrict__ bb,
    float* __restrict__ Wp, float* __restrict__ bp,
    u32* __restrict__ hist, u32* __restrict__ ctl)
{
  int tt = blockIdx.x * 256 + threadIdx.x;
  int k = tt >> 6, o = tt & 63;
  float v = (o < 18) ? Ws[k * 18 + o] : ((o < 54) ? Wb[k * 36 + (o - 18)] : 0.f);
  Wp[tt] = v;
  if (tt < 64) bp[tt] = (tt < 18) ? bs[tt] : ((tt < 54) ? bb[tt - 18] : 0.f);
  if (tt < 256) hist[tt] = 0;
  if (tt < 16) ctl[tt] = 0;
  if (tt == 1) ctl[1] = PRE_NMS_N;   // kneed
}

// ---------------------------------------------------------------------------
// Head GEMM + fused decode: 472 blocks x 32 rows.
// ---------------------------------------------------------------------------
__global__ __launch_bounds__(256) void k_headdec(
    const float* __restrict__ rpn, const float* __restrict__ Wp,
    const float* __restrict__ bp, const int* __restrict__ img,
    float* __restrict__ fg, float4* __restrict__ boxes)
{
  __shared__ float As[32][33];
  __shared__ float Bs[32][64];
  __shared__ float vs[32 * 64];
  const int tid = threadIdx.x;
  const int bm = blockIdx.x * 32;
  const int r  = tid >> 3;          // row 0..31 (load & compute)
  const int kg = tid & 7;           // A-load k-group
  const int c8 = (tid & 7) * 8;     // compute col base
  const int n4 = (tid & 15) * 4;    // B-load
  const int kr = tid >> 4;          // B-load row 0..15
  const float4 z4 = make_float4(0.f, 0.f, 0.f, 0.f);

  float acc[8];
  #pragma unroll
  for (int j = 0; j < 8; ++j) acc[j] = 0.f;

  for (int kc = 0; kc < 512; kc += 32) {
    __syncthreads();
    {
      int m = bm + r;
      float4 v = (m < NPIX) ? *(const float4*)&rpn[(size_t)m * CMID + kc + kg * 4] : z4;
      As[kg * 4 + 0][r] = v.x; As[kg * 4 + 1][r] = v.y;
      As[kg * 4 + 2][r] = v.z; As[kg * 4 + 3][r] = v.w;
    }
    *(float4*)&Bs[kr][n4]      = *(const float4*)&Wp[(kc + kr) * 64 + n4];
    *(float4*)&Bs[kr + 16][n4] = *(const float4*)&Wp[(kc + kr + 16) * 64 + n4];
    __syncthreads();
    #pragma unroll
    for (int kk = 0; kk < 32; ++kk) {
      float a = As[kk][r];
      float4 b0 = *(const float4*)&Bs[kk][c8];
      float4 b1 = *(const float4*)&Bs[kk][c8 + 4];
      acc[0] = fmaf(a, b0.x, acc[0]); acc[1] = fmaf(a, b0.y, acc[1]);
      acc[2] = fmaf(a, b0.z, acc[2]); acc[3] = fmaf(a, b0.w, acc[3]);
      acc[4] = fmaf(a, b1.x, acc[4]); acc[5] = fmaf(a, b1.y, acc[5]);
      acc[6] = fmaf(a, b1.z, acc[6]); acc[7] = fmaf(a, b1.w, acc[7]);
    }
  }
  __syncthreads();
  #pragma unroll
  for (int j = 0; j < 8; ++j) vs[r * 64 + c8 + j] = acc[j] + bp[c8 + j];
  __syncthreads();

  const float AW[9] = {184.f, 368.f, 736.f, 128.f, 256.f, 512.f,  88.f, 176.f, 352.f};
  const float AH[9] = { 96.f, 192.f, 384.f, 128.f, 256.f, 512.f, 176.f, 352.f, 704.f};
  const float imh1 = (float)img[0] - 1.f;
  const float imw1 = (float)img[1] - 1.f;
  for (int id = tid; id < 32 * 9; id += 256) {
    int pl = id / 9, a = id - pl * 9;
    int p = bm + pl;
    if (p >= NPIX) break;
    const float* row = vs + pl * 64;
    const int y = p / W_FM, x = p - y * W_FM;

    float c0 = row[2 * a], c1 = row[2 * a + 1];
    float score = 1.f / (1.f + expf(c0 - c1));

    float dxv = row[18 + 4 * a + 0];
    float dyv = row[18 + 4 * a + 1];
    float dwv = row[18 + 4 * a + 2];
    float dhv = row[18 + 4 * a + 3];

    float aw = AW[a], ah = AH[a];
    float acx = (float)(x * 16 + 8);
    float acy = (float)(y * 16 + 8);
    float pcx = dxv * aw + acx;
    float pcy = dyv * ah + acy;
    float pw = expf(dwv) * aw;
    float ph = expf(dhv) * ah;

    float b0 = fminf(fmaxf(pcx - 0.5f * pw, 0.f), imw1);
    float b1 = fminf(fmaxf(pcy - 0.5f * ph, 0.f), imh1);
    float b2 = fminf(fmaxf(pcx + 0.5f * pw, 0.f), imw1);
    float b3 = fminf(fmaxf(pcy + 0.5f * ph, 0.f), imh1);

    float bw = b2 - b0 + 1.f, bh = b3 - b1 + 1.f;
    if (!(bw >= 16.f && bh >= 16.f)) score = -1e9f;

    int gi = p * 9 + a;
    fg[gi] = score;
    boxes[gi] = make_float4(b0, b1, b2, b3);
  }
}

// ---------------------------------------------------------------------------
// Radix-select (exact top-6000 threshold).
// ctl[0]=prefix/threshold, ctl[1]=kneed, ctl[2]=cntA, ctl[3]=cntB, ctl[8]=nvalid
// ---------------------------------------------------------------------------
__global__ __launch_bounds__(256) void k_hist(
    const float* __restrict__ fg, u32* __restrict__ hist,
    const u32* __restrict__ ctl, int pass)
{
  __shared__ u32 h[256];
  h[threadIdx.x] = 0;
  __syncthreads();
  const int shift = 24 - 8 * pass;
  const u32 prefix = ctl[0];
  for (int i = blockIdx.x * 256 + threadIdx.x; i < NANCH; i += 128 * 256) {
    u32 key = fkey(fg[i]);
    bool match = (pass == 0) || ((key >> (shift + 8)) == prefix);
    if (match) atomicAdd(&h[(key >> shift) & 255], 1u);
  }
  __syncthreads();
  u32 c = h[threadIdx.x];
  if (c) atomicAdd(&hist[threadIdx.x], c);
}

__global__ void k_scan(u32* __restrict__ hist, u32* __restrict__ ctl) {
  if (threadIdx.x == 0) {
    u32 kneed = ctl[1];
    u32 cum = 0;
    int d = 0;
    for (int dd = 255; dd >= 0; --dd) {
      u32 c = hist[dd];
      if (cum + c >= kneed) { d = dd; break; }
      cum += c;
    }
    ctl[0] = (ctl[0] << 8) | (u32)d;
    ctl[1] = kneed - cum;
  }
  __syncthreads();
  hist[threadIdx.x] = 0;
}

__global__ __launch_bounds__(256) void k_compact(
    const float* __restrict__ fg, u32* __restrict__ ctl,
    u64* __restrict__ listA, u32* __restrict__ listB)
{
  int i = blockIdx.x * 256 + threadIdx.x;
  if (i >= NANCH) return;
  u32 T = ctl[0];
  u32 key = fkey(fg[i]);
  if (key > T) {
    u32 slot = atomicAdd(&ctl[2], 1u);
    listA[slot] = ((u64)key << 32) | (u64)(0xFFFFFFFFu - (u32)i);
  } else if (key == T) {
    u32 slot = atomicAdd(&ctl[3], 1u);
    if (slot < 8192) listB[slot] = (u32)i;
  }
}

__global__ __launch_bounds__(256) void k_tiefix(
    u32* __restrict__ ctl, const u32* __restrict__ listB, u64* __restrict__ listA)
{
  __shared__ u32 s[8192];
  const int tid = threadIdx.x;
  const u32 kneed = ctl[1];
  const u32 base = ctl[2];
  const u32 cntB = min(ctl[3], 8192u);
  const u32 T = ctl[0];
  if (kneed == 0) return;
  if (cntB == kneed) {
    for (u32 t = tid; t < kneed; t += 256)
      listA[base + t] = ((u64)T << 32) | (u64)(0xFFFFFFFFu - listB[t]);
    return;
  }
  u32 n2 = 1;
  while (n2 < cntB) n2 <<= 1;
  for (u32 i = tid; i < n2; i += 256) s[i] = (i < cntB) ? listB[i] : 0xFFFFFFFFu;
  __syncthreads();
  for (u32 k = 2; k <= n2; k <<= 1) {
    for (u32 j = k >> 1; j > 0; j >>= 1) {
      for (u32 i = tid; i < n2; i += 256) {
        u32 ixj = i ^ j;
        if (ixj > i) {
          u32 a = s[i], b = s[ixj];
          bool up = ((i & k) == 0);
          if ((a > b) == up) { s[i] = b; s[ixj] = a; }
        }
      }
      __syncthreads();
    }
  }
  for (u32 t = tid; t < kneed; t += 256)
    listA[base + t] = ((u64)T << 32) | (u64)(0xFFFFFFFFu - s[t]);
}

__global__ __launch_bounds__(1024) void k_sort(
    const u64* __restrict__ listA, u64* __restrict__ sorted)
{
  __shared__ u64 s[8192];
  const int tid = threadIdx.x;
  for (int i = tid; i < 8192; i += 1024) s[i] = (i < PRE_NMS_N) ? listA[i] : 0ull;
  __syncthreads();
  for (int k = 2; k <= 8192; k <<= 1) {
    for (int j = k >> 1; j > 0; j >>= 1) {
      for (int i = tid; i < 8192; i += 1024) {
        int ixj = i ^ j;
        if (ixj > i) {
          u64 a = s[i], b = s[ixj];
          bool up = ((i & k) == 0);
          if ((a < b) == up) { s[i] = b; s[ixj] = a; }
        }
      }
      __syncthreads();
    }
  }
  for (int i = tid; i < 8192; i += 1024) sorted[i] = s[i];
}

// gather top boxes; fused: count valid (score > -1e8) into ctl[8]
__global__ __launch_bounds__(256) void k_gather(
    const u64* __restrict__ sorted, const float4* __restrict__ boxes,
    float4* __restrict__ tb, u32* __restrict__ ctl)
{
  int t = blockIdx.x * 256 + threadIdx.x;
  const u32 kcut = fkey(-1e8f);
  bool inb = t < PRE_NMS_N;
  u64 p = inb ? sorted[t] : 0ull;
  bool valid = inb && ((u32)(p >> 32) > kcut);
  u64 ball = __ballot(valid);
  if ((threadIdx.x & 63) == 0 && ball) atomicAdd(&ctl[8], (u32)__popcll(ball));
  if (!inb) return;
  u32 idx = 0xFFFFFFFFu - (u32)(p & 0xFFFFFFFFull);
  tb[t] = boxes[idx];
}

// ---------------------------------------------------------------------------
// Suppression bitmask: mask[i][w] bit b == (IoU(i, w*64+b) > 0.7 && j > i)
// ---------------------------------------------------------------------------
__global__ __launch_bounds__(64) void k_mask(
    const float4* __restrict__ tb, u64* __restrict__ mask)
{
  __shared__ float4 cb[64];
  const int bj = blockIdx.x, bi = blockIdx.y, t = threadIdx.x;
  const int j0 = bj * 64;
  const int jn = min(64, PRE_NMS_N - j0);
  if (t < jn) cb[t] = tb[j0 + t];
  __syncthreads();
  const int i = bi * 64 + t;
  if (i >= PRE_NMS_N) return;
  const float4 b = tb[i];
  const float ai = (b.z - b.x + 1.f) * (b.w - b.y + 1.f);
  u64 bits = 0;
  for (int tt = 0; tt < jn; ++tt) {
    int j = j0 + tt;
    if (j <= i) continue;
    float4 c = cb[tt];
    float iw = fminf(b.z, c.z) - fmaxf(b.x, c.x) + 1.f;
    float ih = fminf(b.w, c.w) - fmaxf(b.y, c.y) + 1.f;
    float inter = fmaxf(iw, 0.f) * fmaxf(ih, 0.f);
    float aj = (c.z - c.x + 1.f) * (c.w - c.y + 1.f);
    float iou = inter / (ai + aj - inter);
    if (iou > 0.7f) bits |= (1ull << tt);
  }
  mask[(size_t)i * WPR + bj] = bits;
}

// ---------------------------------------------------------------------------
// Single-wave greedy NMS walk, word-level ffs scanning over live bits.
// removed-bitmask in registers (lane -> words lane, lane+64). Early exit @300.
// ---------------------------------------------------------------------------
__global__ __launch_bounds__(64) void k_nms(
    const u64* __restrict__ mask, const float* __restrict__ tb,
    const u32* __restrict__ ctl, float* __restrict__ out)
{
  const int lane = threadIdx.x;
  const int nvalid = min((int)ctl[8], PRE_NMS_N);
  u64 r0 = 0, r1 = 0;
  int kept = 0;
  for (int w = 0; w < WPR && kept < POST_NMS_N; ++w) {
    const int base = w << 6;
    if (base >= nvalid) break;
    u64 rw = (w < 64) ? shfl64(r0, w) : shfl64(r1, w - 64);
    u64 live = ~rw;
    if (base + 64 > nvalid) live &= ((1ull << (nvalid - base)) - 1ull);
    while (live) {
      int b = (int)(__ffsll((long long)live) - 1);
      int i = base + b;
      if (lane < 4) out[kept * 4 + lane] = tb[i * 4 + lane];
      ++kept;
      if (kept >= POST_NMS_N) break;
      const u64* row = mask + (size_t)i * WPR;
      u64 m0 = row[lane];
      u64 m1 = (lane < WPR - 64) ? row[64 + lane] : 0ull;
      r0 |= m0; r1 |= m1;
      u64 rwi = (w < 64) ? shfl64(m0, w) : shfl64(m1, w - 64);
      live &= ~rwi;
      live = (b == 63) ? 0ull : (live & (~0ull << (b + 1)));
    }
  }
  for (int j = kept * 4 + lane; j < POST_NMS_N * 4; j += 64) out[j] = 0.f;
}

// ---------------------------------------------------------------------------
extern "C" void kernel_launch(void* const* d_in, const int* in_sizes, int n_in,
                              void* d_out, int out_size, void* d_ws, size_t ws_size,
                              hipStream_t stream) {
  const float* fm  = (const float*)d_in[0];
  const float* Wr  = (const float*)d_in[1];
  const float* br  = (const float*)d_in[2];
  const float* Wsc = (const float*)d_in[3];
  const float* bsc = (const float*)d_in[4];
  const float* Wbb = (const float*)d_in[5];
  const float* bbb = (const float*)d_in[6];
  const int*   img = (const int*)d_in[7];
  float* out = (float*)d_out;

  char* w = (char*)d_ws;
  size_t off = 0;
  auto alloc = [&](size_t bytes) {
    size_t p = off;
    off = (off + bytes + 255) & ~(size_t)255;
    return p;
  };
  float* rpn    = (float*)(w + alloc((size_t)NPIX * CMID * 4));       // 30.72 MB
  float* fg     = (float*)(w + alloc((size_t)NANCH * 4));
  float4* boxes = (float4*)(w + alloc((size_t)NANCH * 16));
  u32* hist     = (u32*)(w + alloc(1024));
  u32* ctl      = (u32*)(w + alloc(64));
  u64* listA    = (u64*)(w + alloc((size_t)PRE_NMS_N * 8));
  u32* listB    = (u32*)(w + alloc(8192 * 4));
  u64* sorted   = (u64*)(w + alloc(8192 * 8));
  float4* topbox= (float4*)(w + alloc((size_t)PRE_NMS_N * 16));
  u64* mask     = (u64*)(w + alloc((size_t)PRE_NMS_N * WPR * 8));     // 4.5 MB
  float* Wp     = (float*)(w + alloc(512 * 64 * 4));
  float* bp     = (float*)(w + alloc(64 * 4));
  unsigned short* Ap = (unsigned short*)(w + alloc((size_t)(3 * ASPLIT))); // 97.1 MB
  unsigned short* Bp = (unsigned short*)(w + alloc((size_t)(3 * BSPLIT))); // 28.3 MB

  // 1. precision-split + pack (halo-zero fused in splitA; hist/ctl init in packW)
  k_splitA<<<dim3((32 * NPIX + 255) / 256), dim3(256), 0, stream>>>(fm, Ap);
  k_splitB<<<dim3(144, 8), dim3(256), 0, stream>>>(Wr, Bp);
  k_packW<<<dim3(128), dim3(256), 0, stream>>>(Wsc, bsc, Wbb, bbb, Wp, bp, hist, ctl);
  // 2. conv (3x3 + bias + relu), XCD-swizzled pipelined MFMA
  k_conv8<<<dim3(480), dim3(256), 0, stream>>>(Ap, Bp, br, rpn);
  // 3. heads + fused decode
  k_headdec<<<dim3(472), dim3(256), 0, stream>>>(rpn, Wp, bp, img, fg, boxes);
  // 4. exact top-6000 radix select
  for (int pass = 0; pass < 4; ++pass) {
    k_hist<<<128, 256, 0, stream>>>(fg, hist, ctl, pass);
    k_scan<<<1, 256, 0, stream>>>(hist, ctl);
  }
  k_compact<<<(NANCH + 255) / 256, 256, 0, stream>>>(fg, ctl, listA, listB);
  k_tiefix<<<1, 256, 0, stream>>>(ctl, listB, listA);
  // 5. sort (desc score, asc index) + gather (+ valid count)
  k_sort<<<1, 1024, 0, stream>>>(listA, sorted);
  k_gather<<<(PRE_NMS_N + 255) / 256, 256, 0, stream>>>(sorted, boxes, topbox, ctl);
  // 6. NMS mask + single-wave ffs walk + emit 300
  k_mask<<<dim3(WPR, WPR), 64, 0, stream>>>(topbox, mask);
  k_nms<<<1, 64, 0, stream>>>(mask, (const float*)topbox, ctl, out);
}